// Round 6
// baseline (96.770 us; speedup 1.0000x reference)
//
#include <hip/hip_runtime.h>
#include <hip/hip_fp16.h>
#include <hip/hip_bf16.h>

#define TL 3000
#define NN 30000
#define DIM 128
#define KNEG 75
#define NQL (2 * TL)
#define EPSF 1e-7f
#define MAXSQ 50.0f

#define ESUB 512          // candidate subsample for the count gate
#define NSPL 4            // candidate splits (blocks per query tile)
#define ECHS 128          // candidate rows per split (32 KB LDS)
#define QT 64             // query rows per block
#define QBLK 94           // ceil(6000/64)
#define QS (QBLK * QT)    // 6016
#define FLAGTH 125        // KNEG + 50 margin vs expected ~236 clipped in 512
#define NORM (1.0f / (2.0f * (float)KNEG * (float)TL))

typedef __attribute__((ext_vector_type(8))) short bf16x8;
typedef __attribute__((ext_vector_type(4))) float f32x4;

__device__ __forceinline__ int wred_i(int v) {
#pragma unroll
  for (int o = 32; o > 0; o >>= 1) v += __shfl_xor(v, o, 64);
  return v;
}
__device__ __forceinline__ float wred_f(float v) {
#pragma unroll
  for (int o = 32; o > 0; o >>= 1) v += __shfl_xor(v, o, 64);
  return v;
}

__device__ __forceinline__ float sqdist_f(float prod, float cv, float K) {
  float theta = fmaxf(-prod * cv, 1.0f + EPSF);
  float a = acoshf(theta);
  return fminf(K * a * a, MAXSQ);
}

__device__ __forceinline__ unsigned short to_bf16(float x) {
  __hip_bfloat16 h = __float2bfloat16(x);
  return *(unsigned short*)&h;
}

// ---------- count kernel: block (qt,spl) counts 64 queries x 128 candidates ----------
// All workspace writes unconditional & disjoint — no zero-init needed anywhere.
__launch_bounds__(256)
__global__ void count_kernel(const float* __restrict__ emb, const float* __restrict__ c,
                             const int* __restrict__ links, int* __restrict__ cnt_ws,
                             float* __restrict__ contrib_ws, float* __restrict__ Dq_ws) {
  __shared__ __align__(16) unsigned short Es[ECHS * DIM];  // 32 KB
  const int tid = threadIdx.x;
  const int lane = tid & 63;
  const int w = tid >> 6;
  const int am = lane & 15;
  const int aq = lane >> 4;
  const int qt = blockIdx.x >> 2;
  const int spl = blockIdx.x & 3;
  const float cv = c[0];
  const float K = 1.0f / cv;
  const float thresh = -(1.0f + EPSF) / cv;

  // A fragments: gather 64 query rows (fp32 -> bf16). A[m=lane&15][k=kc*32+aq*8+j];
  // k==0 negated so prod = dot(q', e) with q'[0] = -q[0].
  bf16x8 A[4][4];
#pragma unroll
  for (int mg = 0; mg < 4; ++mg) {
    int q = qt * QT + mg * 16 + am;
    int node = 0;
    if (q < NQL) {
      int li = (q < TL) ? q : q - TL;
      node = (q < TL) ? links[2 * li] : links[2 * li + 1];
    }
    const float* qr = emb + (size_t)node * DIM;
#pragma unroll
    for (int kc = 0; kc < 4; ++kc) {
      float4 f0 = *(const float4*)(qr + kc * 32 + aq * 8);
      float4 f1 = *(const float4*)(qr + kc * 32 + aq * 8 + 4);
      if (kc == 0 && aq == 0) f0.x = -f0.x;
      bf16x8 v;
      v[0] = (short)to_bf16(f0.x); v[1] = (short)to_bf16(f0.y);
      v[2] = (short)to_bf16(f0.z); v[3] = (short)to_bf16(f0.w);
      v[4] = (short)to_bf16(f1.x); v[5] = (short)to_bf16(f1.y);
      v[6] = (short)to_bf16(f1.z); v[7] = (short)to_bf16(f1.w);
      A[mg][kc] = v;
    }
  }

  // Stage this split's 128 candidate rows in B-fragment order. Wave w writes
  // exactly the slot-groups (sg = 2w, 2w+1) it will MFMA — wave-internal LDS
  // ordering (lgkmcnt) suffices, no barrier.
#pragma unroll
  for (int i = 0; i < 8; ++i) {
    int g = w * 8 + i;  // slot-group: sg = g>>2 (0..7), kc = g&3
    int sg = g >> 2, kc = g & 3;
    const float* src = emb + (size_t)(spl * ECHS + sg * 16 + am) * DIM + kc * 32 + aq * 8;
    float4 f0 = *(const float4*)src;
    float4 f1 = *(const float4*)(src + 4);
    bf16x8 v;
    v[0] = (short)to_bf16(f0.x); v[1] = (short)to_bf16(f0.y);
    v[2] = (short)to_bf16(f0.z); v[3] = (short)to_bf16(f0.w);
    v[4] = (short)to_bf16(f1.x); v[5] = (short)to_bf16(f1.y);
    v[6] = (short)to_bf16(f1.z); v[7] = (short)to_bf16(f1.w);
    *(bf16x8*)&Es[(g * 64 + lane) * 8] = v;
  }

  int cnt[4][4];
#pragma unroll
  for (int mg = 0; mg < 4; ++mg)
#pragma unroll
    for (int r = 0; r < 4; ++r) cnt[mg][r] = 0;

#pragma unroll
  for (int s2 = 0; s2 < 2; ++s2) {
    int sg = w * 2 + s2;
    f32x4 a0 = {0.f, 0.f, 0.f, 0.f}, a1 = {0.f, 0.f, 0.f, 0.f};
    f32x4 a2 = {0.f, 0.f, 0.f, 0.f}, a3 = {0.f, 0.f, 0.f, 0.f};
#pragma unroll
    for (int kc = 0; kc < 4; ++kc) {
      bf16x8 B = *(const bf16x8*)&Es[((sg * 4 + kc) * 64 + lane) * 8];
      a0 = __builtin_amdgcn_mfma_f32_16x16x32_bf16(A[0][kc], B, a0, 0, 0, 0);
      a1 = __builtin_amdgcn_mfma_f32_16x16x32_bf16(A[1][kc], B, a1, 0, 0, 0);
      a2 = __builtin_amdgcn_mfma_f32_16x16x32_bf16(A[2][kc], B, a2, 0, 0, 0);
      a3 = __builtin_amdgcn_mfma_f32_16x16x32_bf16(A[3][kc], B, a3, 0, 0, 0);
    }
#pragma unroll
    for (int r = 0; r < 4; ++r) {
      cnt[0][r] += (a0[r] >= thresh);
      cnt[1][r] += (a1[r] >= thresh);
      cnt[2][r] += (a2[r] >= thresh);
      cnt[3][r] += (a3[r] >= thresh);
    }
  }

  // cross-wave count reduction in LDS (reuse Es after all MFMA reads done)
  __syncthreads();
  int* lc = (int*)&Es[0];
  if (tid < QT) lc[tid] = 0;
  __syncthreads();
#pragma unroll
  for (int mg = 0; mg < 4; ++mg)
#pragma unroll
    for (int r = 0; r < 4; ++r) {
      int v = cnt[mg][r];
      v += __shfl_xor(v, 1, 64);
      v += __shfl_xor(v, 2, 64);
      v += __shfl_xor(v, 4, 64);
      v += __shfl_xor(v, 8, 64);
      if (am == 0) atomicAdd(&lc[mg * 16 + aq * 4 + r], v);
    }
  __syncthreads();
  if (tid < QT) cnt_ws[spl * QS + qt * QT + tid] = lc[tid];

  // spl==0 blocks also produce Dq and the closed-form contribution per query
  if (spl == 0 && tid < QT) {
    int q = qt * QT + tid;
    if (q < NQL) {
      int li = (q < TL) ? q : q - TL;
      long l = links[2 * li];
      long r = links[2 * li + 1];
      const float4* x = (const float4*)(emb + l * DIM);
      const float4* y = (const float4*)(emb + r * DIM);
      float dot = 0.f, x0 = 0.f, y0 = 0.f;
#pragma unroll
      for (int k = 0; k < 32; ++k) {
        float4 a = x[k], b = y[k];
        if (k == 0) { x0 = a.x; y0 = b.x; }
        dot = fmaf(a.x, b.x, dot);
        dot = fmaf(a.y, b.y, dot);
        dot = fmaf(a.z, b.z, dot);
        dot = fmaf(a.w, b.w, dot);
      }
      float Dq = sqdist_f(dot - 2.0f * x0 * y0, cv, K) + 1.0f;  // + GAMMA
      float acl = acoshf(1.0f + EPSF);
      float clipv = fminf(K * acl * acl, MAXSQ);
      Dq_ws[q] = Dq;
      contrib_ws[q] = (float)KNEG * fmaxf(Dq - clipv, 0.f);
    }
  }
}

// ---------- final: gate + sum + exact fallback for flagged (normally none) ----------
__launch_bounds__(256)
__global__ void final_kernel(const float* __restrict__ emb, const float* __restrict__ c,
                             const int* __restrict__ links, const int* __restrict__ cnt_ws,
                             const float* __restrict__ contrib_ws,
                             const float* __restrict__ Dq_ws, int* __restrict__ list_ws,
                             float* __restrict__ out) {
  __shared__ __align__(16) float qvec[DIM];
  __shared__ unsigned short s16[NN];  // 60000 B (fallback scratch)
  __shared__ int ish[4];
  __shared__ float fsh[4];
  __shared__ float acc_total;
  __shared__ int nflag;
  const int tid = threadIdx.x;
  if (tid == 0) nflag = 0;
  __syncthreads();

  float acc = 0.f;
  for (int q = tid; q < NQL; q += 256) {
    int ct = cnt_ws[q] + cnt_ws[QS + q] + cnt_ws[2 * QS + q] + cnt_ws[3 * QS + q];
    if (ct >= FLAGTH) {
      acc += contrib_ws[q];
    } else {
      int p = atomicAdd(&nflag, 1);
      list_ws[p] = q;
    }
  }
  acc = wred_f(acc);
  if ((tid & 63) == 0) fsh[tid >> 6] = acc;
  __syncthreads();
  if (tid == 0) acc_total = fsh[0] + fsh[1] + fsh[2] + fsh[3];
  __syncthreads();

  const float cv = c[0];
  const float K = 1.0f / cv;
  const int nf = nflag;

  for (int it = 0; it < nf; ++it) {
    const int q = list_ws[it];
    const int li = (q < TL) ? q : q - TL;
    const int node = (q < TL) ? links[2 * li] : links[2 * li + 1];
    const float Dq = Dq_ws[q];

    if (tid < DIM) qvec[tid] = emb[(long)node * DIM + tid];
    __syncthreads();
    const float q0 = qvec[0];
    const float4* q4 = (const float4*)qvec;

    for (int jj = tid; jj < NN; jj += 256) {
      const float4* row = (const float4*)(emb + (long)jj * DIM);
      float dacc = 0.f, e0 = 0.f;
#pragma unroll
      for (int k = 0; k < DIM / 4; ++k) {
        float4 e = row[k];
        float4 v = q4[k];
        if (k == 0) e0 = e.x;
        dacc = fmaf(e.x, v.x, dacc);
        dacc = fmaf(e.y, v.y, dacc);
        dacc = fmaf(e.z, v.z, dacc);
        dacc = fmaf(e.w, v.w, dacc);
      }
      float s = sqdist_f(dacc - 2.0f * e0 * q0, cv, K);
      s16[jj] = __half_as_ushort(__float2half_rn(s));
    }
    __syncthreads();

    unsigned int lo = 0, hi = 0xFFFFu;
    while (lo < hi) {
      unsigned int mid = (lo + hi) >> 1;
      int cnt = 0;
      for (int jj = tid; jj < NN; jj += 256) cnt += (s16[jj] <= mid) ? 1 : 0;
      cnt = wred_i(cnt);
      if ((tid & 63) == 0) ish[tid >> 6] = cnt;
      __syncthreads();
      int tot = ish[0] + ish[1] + ish[2] + ish[3];
      if (tot >= KNEG) hi = mid; else lo = mid + 1;
      __syncthreads();
    }
    const unsigned int T = lo;
    const float Tval = __half2float(__ushort_as_half((unsigned short)T));

    int nl = 0;
    float sum = 0.f;
    for (int jj = tid; jj < NN; jj += 256) {
      unsigned short k = s16[jj];
      if ((unsigned int)k < T) {
        nl++;
        sum += fmaxf(Dq - __half2float(__ushort_as_half(k)), 0.f);
      }
    }
    nl = wred_i(nl);
    sum = wred_f(sum);
    if ((tid & 63) == 0) { ish[tid >> 6] = nl; fsh[tid >> 6] = sum; }
    __syncthreads();
    if (tid == 0) {
      int n_less = ish[0] + ish[1] + ish[2] + ish[3];
      float s = fsh[0] + fsh[1] + fsh[2] + fsh[3];
      s += (float)(KNEG - n_less) * fmaxf(Dq - Tval, 0.f);
      acc_total += s;
    }
    __syncthreads();
  }

  if (tid == 0) out[0] = acc_total * NORM;
}

extern "C" void kernel_launch(void* const* d_in, const int* in_sizes, int n_in,
                              void* d_out, int out_size, void* d_ws, size_t ws_size,
                              hipStream_t stream) {
  const float* emb = (const float*)d_in[0];
  const float* c = (const float*)d_in[1];
  const int* links = (const int*)d_in[2];
  float* out = (float*)d_out;

  int* cnt_ws = (int*)d_ws;                       // 4 * 6016 ints
  float* contrib_ws = (float*)(cnt_ws + NSPL * QS);  // 6016 floats
  float* Dq_ws = contrib_ws + QS;                 // 6016 floats
  int* list_ws = (int*)(Dq_ws + QS);              // 6016 ints

  count_kernel<<<QBLK * NSPL, 256, 0, stream>>>(emb, c, links, cnt_ws, contrib_ws, Dq_ws);
  final_kernel<<<1, 256, 0, stream>>>(emb, c, links, cnt_ws, contrib_ws, Dq_ws, list_ws,
                                      out);
}